// Round 2
// baseline (3682.650 us; speedup 1.0000x reference)
//
#include <hip/hip_runtime.h>
#include <hip/hip_bf16.h>

// ---------------------------------------------------------------------------
// CRQ-VAE forward: encoder MLP (768->512->256->64, relu,relu,none) + 4-level
// residual VQ (K=256, e=64) with loss and codes.
// Outputs (flat): x_q [N*64] f32, rq_loss [1] f32, codes [4*N] f32.
// Argmin ranking done in fp64 so code selection is exact given our residual.
// ---------------------------------------------------------------------------

#define GBM 128
#define GBN 64
#define GBK 16
#define GTM 8
#define GTN 4

// C[M,N] = act(A[M,K] @ W[K,N] + bias[N]);  M%128==0, N%64==0, K%16==0
template<bool RELU>
__global__ __launch_bounds__(256) void gemm_bias(
    const float* __restrict__ A, const float* __restrict__ W,
    const float* __restrict__ bias, float* __restrict__ C,
    int M, int N, int K)
{
    __shared__ float As[GBK][GBM + 4];
    __shared__ float Bs[GBK][GBN + 4];

    const int tid = threadIdx.x;
    const int tx = tid & 15;
    const int ty = tid >> 4;
    const int col0 = blockIdx.x * GBN;
    const int row0 = blockIdx.y * GBM;

    const float* Ab = A + (size_t)row0 * K;
    const float* Wb = W + col0;

    float acc[GTM][GTN] = {};

    for (int k0 = 0; k0 < K; k0 += GBK) {
#pragma unroll
        for (int i = 0; i < 2; ++i) {
            int pos = tid + i * 256;
            int m  = pos >> 2;
            int k4 = (pos & 3) * 4;
            float4 v = *reinterpret_cast<const float4*>(Ab + (size_t)m * K + k0 + k4);
            As[k4 + 0][m] = v.x; As[k4 + 1][m] = v.y;
            As[k4 + 2][m] = v.z; As[k4 + 3][m] = v.w;
        }
        {
            int kk = tid >> 4;
            int n4 = (tid & 15) * 4;
            float4 v = *reinterpret_cast<const float4*>(Wb + (size_t)(k0 + kk) * N + n4);
            *reinterpret_cast<float4*>(&Bs[kk][n4]) = v;
        }
        __syncthreads();
#pragma unroll
        for (int kk = 0; kk < GBK; ++kk) {
            float4 a0 = *reinterpret_cast<const float4*>(&As[kk][ty * GTM]);
            float4 a1 = *reinterpret_cast<const float4*>(&As[kk][ty * GTM + 4]);
            float4 bv = *reinterpret_cast<const float4*>(&Bs[kk][tx * GTN]);
            float a[GTM] = {a0.x, a0.y, a0.z, a0.w, a1.x, a1.y, a1.z, a1.w};
            float b[GTN] = {bv.x, bv.y, bv.z, bv.w};
#pragma unroll
            for (int m = 0; m < GTM; ++m)
#pragma unroll
                for (int n = 0; n < GTN; ++n)
                    acc[m][n] = fmaf(a[m], b[n], acc[m][n]);
        }
        __syncthreads();
    }

    float bv[GTN];
#pragma unroll
    for (int n = 0; n < GTN; ++n) bv[n] = bias[col0 + tx * GTN + n];
#pragma unroll
    for (int m = 0; m < GTM; ++m) {
        int row = row0 + ty * GTM + m;
        float4 o;
        float v0 = acc[m][0] + bv[0];
        float v1 = acc[m][1] + bv[1];
        float v2 = acc[m][2] + bv[2];
        float v3 = acc[m][3] + bv[3];
        if (RELU) {
            v0 = fmaxf(v0, 0.f); v1 = fmaxf(v1, 0.f);
            v2 = fmaxf(v2, 0.f); v3 = fmaxf(v3, 0.f);
        }
        o.x = v0; o.y = v1; o.z = v2; o.w = v3;
        *reinterpret_cast<float4*>(C + (size_t)row * N + col0 + tx * GTN) = o;
    }
}

// ---------------------------------------------------------------------------
// codebook norms in fp64: cn[l*256+c] = sum_j cb[l][c][j]^2
__global__ void cb_norms(const float* __restrict__ cb, double* __restrict__ cn) {
    int c = blockIdx.x * 64 + threadIdx.x;   // 16 blocks x 64
    const float* p = cb + (size_t)c * 64;
    double s = 0.0;
#pragma unroll
    for (int j = 0; j < 64; ++j) {
        double v = (double)p[j];
        s = fma(v, v, s);
    }
    cn[c] = s;
}

// ---------------------------------------------------------------------------
// RVQ: 64 rows per block (row = lane), 4 waves split the 256 codes.
// Residual carried as fp64 widening of the fp32 residual chain; distance
// ranking in fp64 (exact argmin given residual). fp32 elementwise residual
// update matches the reference's op-for-op.
#define CBCH 64

__global__ __launch_bounds__(256) void rvq_kernel(
    const float* __restrict__ z,       // [cur, 64] chunk-local
    const float* __restrict__ cb,      // [4,256,64]
    const double* __restrict__ cn,     // [4*256] fp64 code norms
    float* __restrict__ xq,            // d_out base [N,64]
    float* __restrict__ codes,         // d_out codes base [4,N]
    double* __restrict__ partials,     // [N/64]
    int row0, int Ntot)
{
    __shared__ float  zs[64][65];
    __shared__ float  cbs[CBCH][68];
    __shared__ double cns[CBCH];
    __shared__ double red_d[4][64];
    __shared__ int    red_i[4][64];

    const int tid  = threadIdx.x;
    const int lane = tid & 63;
    const int w    = tid >> 6;
    const int blk  = blockIdx.x;
    const int grow0 = row0 + blk * 64;

#pragma unroll
    for (int i = 0; i < 4; ++i) {
        int p = tid + i * 256;
        int m  = p >> 4;
        int j4 = (p & 15) * 4;
        float4 v = *reinterpret_cast<const float4*>(z + (size_t)(blk * 64 + m) * 64 + j4);
        zs[m][j4 + 0] = v.x; zs[m][j4 + 1] = v.y;
        zs[m][j4 + 2] = v.z; zs[m][j4 + 3] = v.w;
    }
    __syncthreads();

    double rd[64];
#pragma unroll
    for (int j = 0; j < 64; ++j) rd[j] = (double)zs[lane][j];

    double sse = 0.0;

    for (int l = 0; l < 4; ++l) {
        const float* cbl = cb + (size_t)l * 256 * 64;
        double sr = 0.0;
#pragma unroll
        for (int j = 0; j < 64; ++j) sr = fma(rd[j], rd[j], sr);

        double dmin = 1e300;
        int    imin = 0;

        for (int ch = 0; ch < 256 / CBCH; ++ch) {
            __syncthreads();   // previous chunk consumed (also protects red_*)
#pragma unroll
            for (int i = 0; i < (CBCH * 16) / 256; ++i) {
                int p  = tid + i * 256;
                int cc = p >> 4;
                int j4 = (p & 15) * 4;
                float4 v = *reinterpret_cast<const float4*>(
                    cbl + (size_t)(ch * CBCH + cc) * 64 + j4);
                *reinterpret_cast<float4*>(&cbs[cc][j4]) = v;
            }
            if (tid < CBCH)
                cns[tid] = cn[l * 256 + ch * CBCH + tid];
            __syncthreads();

            const int per = CBCH / 4;
#pragma unroll
            for (int c = 0; c < per; ++c) {
                int cc = w * per + c;
                double dot0 = 0.0, dot1 = 0.0;
#pragma unroll
                for (int q = 0; q < 16; ++q) {
                    float4 cv = *reinterpret_cast<const float4*>(&cbs[cc][q * 4]);
                    dot0 = fma((double)cv.x, rd[q * 4 + 0], dot0);
                    dot1 = fma((double)cv.y, rd[q * 4 + 1], dot1);
                    dot0 = fma((double)cv.z, rd[q * 4 + 2], dot0);
                    dot1 = fma((double)cv.w, rd[q * 4 + 3], dot1);
                }
                double d = (sr + cns[cc]) - 2.0 * (dot0 + dot1);
                int code = ch * CBCH + cc;
                if (d < dmin) { dmin = d; imin = code; }
            }
        }

        // cross-wave argmin combine (first-min tie-break = lowest index)
        red_d[w][lane] = dmin;
        red_i[w][lane] = imin;
        __syncthreads();
        double bd = red_d[0][lane];
        int    bi = red_i[0][lane];
#pragma unroll
        for (int ww = 1; ww < 4; ++ww) {
            double dd = red_d[ww][lane];
            int    ii = red_i[ww][lane];
            if (dd < bd || (dd == bd && ii < bi)) { bd = dd; bi = ii; }
        }

        // gather q, accumulate loss (fp64), fp32 residual update (matches ref)
        const float* qp = cbl + (size_t)bi * 64;
        double lsse = 0.0;
#pragma unroll
        for (int q4 = 0; q4 < 16; ++q4) {
            float4 qv = *reinterpret_cast<const float4*>(qp + q4 * 4);
            float r0 = (float)rd[q4 * 4 + 0];
            float r1 = (float)rd[q4 * 4 + 1];
            float r2 = (float)rd[q4 * 4 + 2];
            float r3 = (float)rd[q4 * 4 + 3];
            float e0 = qv.x - r0, e1 = qv.y - r1;
            float e2 = qv.z - r2, e3 = qv.w - r3;
            lsse = fma((double)e0, (double)e0, lsse);
            lsse = fma((double)e1, (double)e1, lsse);
            lsse = fma((double)e2, (double)e2, lsse);
            lsse = fma((double)e3, (double)e3, lsse);
            rd[q4 * 4 + 0] = (double)(r0 - qv.x);
            rd[q4 * 4 + 1] = (double)(r1 - qv.y);
            rd[q4 * 4 + 2] = (double)(r2 - qv.z);
            rd[q4 * 4 + 3] = (double)(r3 - qv.w);
        }
        sse += lsse;

        if (w == 0)
            codes[(size_t)l * Ntot + grow0 + lane] = (float)bi;
    }

    // x_q = z - r_final ; write by wave 0 only
    if (w == 0) {
        size_t base = (size_t)(grow0 + lane) * 64;
#pragma unroll
        for (int q4 = 0; q4 < 16; ++q4) {
            float4 o;
            o.x = zs[lane][q4 * 4 + 0] - (float)rd[q4 * 4 + 0];
            o.y = zs[lane][q4 * 4 + 1] - (float)rd[q4 * 4 + 1];
            o.z = zs[lane][q4 * 4 + 2] - (float)rd[q4 * 4 + 2];
            o.w = zs[lane][q4 * 4 + 3] - (float)rd[q4 * 4 + 3];
            *reinterpret_cast<float4*>(xq + base + q4 * 4) = o;
        }
        double s = sse;
#pragma unroll
        for (int off = 32; off > 0; off >>= 1) s += __shfl_down(s, off);
        if (lane == 0) partials[grow0 >> 6] = s;
    }
}

// ---------------------------------------------------------------------------
__global__ void loss_final(const double* __restrict__ partials, int n,
                           float* __restrict__ out, double scale) {
    __shared__ double s[256];
    double acc = 0.0;
    for (int i = threadIdx.x; i < n; i += 256) acc += partials[i];
    s[threadIdx.x] = acc;
    __syncthreads();
    for (int off = 128; off > 0; off >>= 1) {
        if ((int)threadIdx.x < off) s[threadIdx.x] += s[threadIdx.x + off];
        __syncthreads();
    }
    if (threadIdx.x == 0) *out = (float)(s[0] * scale);
}

// ---------------------------------------------------------------------------
extern "C" void kernel_launch(void* const* d_in, const int* in_sizes, int n_in,
                              void* d_out, int out_size, void* d_ws, size_t ws_size,
                              hipStream_t stream) {
    const float* x  = (const float*)d_in[0];
    const float* W0 = (const float*)d_in[1];
    const float* b0 = (const float*)d_in[2];
    const float* W1 = (const float*)d_in[3];
    const float* b1 = (const float*)d_in[4];
    const float* W2 = (const float*)d_in[5];
    const float* b2 = (const float*)d_in[6];
    const float* cb = (const float*)d_in[7];

    const int N = in_sizes[0] / 768;

    float* out   = (float*)d_out;
    float* xq    = out;                      // [N*64]
    float* loss  = out + (size_t)N * 64;     // [1]
    float* codes = loss + 1;                 // [4*N]

    const int nblk_total = N / 64;
    // tail: 1024 doubles (cn) + nblk doubles (partials), in float units
    const size_t tail_floats = 2048 + 2 * (size_t)nblk_total;

    size_t avail = ws_size / 4;
    avail = (avail > tail_floats) ? (avail - tail_floats) : 0;
    int Nc = (int)(avail / 832);
    Nc = (Nc / 128) * 128;
    if (Nc > N) Nc = N;
    if (Nc < 128) Nc = 128;

    float* ws = (float*)d_ws;
    float* h0 = ws;
    float* h1 = h0 + (size_t)Nc * 512;
    float* z  = h1 + (size_t)Nc * 256;
    double* cn = (double*)(ws + (size_t)Nc * 832);   // Nc*832*4 bytes, 8B-aligned
    double* partials = cn + 1024;

    cb_norms<<<16, 64, 0, stream>>>(cb, cn);

    for (int r0 = 0; r0 < N; r0 += Nc) {
        int cur = (N - r0 < Nc) ? (N - r0) : Nc;
        gemm_bias<true ><<<dim3(512 / GBN, cur / GBM), 256, 0, stream>>>(
            x + (size_t)r0 * 768, W0, b0, h0, cur, 512, 768);
        gemm_bias<true ><<<dim3(256 / GBN, cur / GBM), 256, 0, stream>>>(
            h0, W1, b1, h1, cur, 256, 512);
        gemm_bias<false><<<dim3( 64 / GBN, cur / GBM), 256, 0, stream>>>(
            h1, W2, b2, z, cur, 64, 256);
        rvq_kernel<<<cur / 64, 256, 0, stream>>>(
            z, cb, cn, xq, codes, partials, r0, N);
    }

    loss_final<<<1, 256, 0, stream>>>(partials, nblk_total, loss,
                                      1.25 / (4.0 * (double)N * 64.0));
}